// Round 5
// baseline (977.777 us; speedup 1.0000x reference)
//
#include <hip/hip_runtime.h>
#include <hip/hip_fp16.h>

#define USER_NUM 200000
#define ITEM_NUM 100000
#define N_NODES  300000   // USER_NUM + ITEM_NUM
#define N_EDGES  9600000
#define D        64
#define NELEM    ((long long)N_NODES * D)       // 19,200,000
#define NELEM4   (NELEM / 4)                    // 4,800,000

// Fixed-capacity bucket per node. deg ~ Poisson(32), max for this dataset
// ~60; CAP=96 leaves huge margin (clamp guards below make OOB impossible).
#define CAP 96

// Slot entry packing: [31:19] = 13-bit weight q (w = q/8191), [18:0] = src id.
#define SRC_MASK 0x7FFFFu
#define W_SCALE  (1.0f / 8191.0f)

// K-dimension (src) slicing: 2 passes per layer. Pass 0 gathers only rows
// with src < SPLIT (cur[0..150K) = 19.2 MB window -> L2-resident), pass 1
// the rest. Round-4 PMC: spmm L2 hit ~48% matched a capacity-limited model
// on the 38.4 MB cur buffer; hard-bounding the per-dispatch window converts
// the 32x per-line reuse into hits.
#define SPLIT 150000

// ---- binned bucket-build geometry (LDS-staged, full-line writes) ----
// Round-1 lesson: any scheme whose scatter goes through global cache lines
// thrashes — in-flight partial lines >> L2 regardless of tuning (measured
// 9.5x WRITE amplification). Pass A = block-local counting sort staged in
// LDS, streamed out as full lines. Pass B = per-bin fill, counters in LDS,
// slot scatter confined to the bin's 384 KB L2-local region.
#define BIN_NODES 1024
#define BIN_SHIFT 10
#define NBINS     ((N_NODES + BIN_NODES - 1) / BIN_NODES)   // 293
#define EPB       7168    // edges per block: stage 56 KB + 2x1.2 KB < 64 KB LDS
#define NBLK_A    ((N_EDGES + EPB - 1) / EPB)               // 1340
#define BPG       ((NBLK_A + 15) / 16)                      // 84 blks per group

// ---------------------------------------------------------------- init
// cur = fp16(all_emb). Final layer reconstructs the layer-sum from the
// per-layer fp16 buffers, so out is never RMW'd across layers.
__global__ void init_kernel(const float4* __restrict__ user_emb,
                            const float4* __restrict__ item_emb,
                            ushort4* __restrict__ cur) {
    long long i = (long long)blockIdx.x * blockDim.x + threadIdx.x;
    if (i >= NELEM4) return;
    const long long user4 = (long long)USER_NUM * D / 4;
    float4 v = (i < user4) ? user_emb[i] : item_emb[i - user4];
    __half h0 = __float2half_rn(v.x), h1 = __float2half_rn(v.y);
    __half h2 = __float2half_rn(v.z), h3 = __float2half_rn(v.w);
    cur[i] = make_ushort4(*(unsigned short*)&h0, *(unsigned short*)&h1,
                          *(unsigned short*)&h2, *(unsigned short*)&h3);
}

// ---------------------------------------------------------------- pass A
// Block-local counting sort of EPB edges by bin, staged in LDS.
// Entry: u64 = (local_node << 32) | (q << 19) | src.
__global__ __launch_bounds__(512) void binA_kernel(
        const int*   __restrict__ src,
        const int*   __restrict__ dst,
        const float* __restrict__ w,
        unsigned long long* __restrict__ seg,
        unsigned*           __restrict__ blk_info) {
    __shared__ unsigned long long stage[EPB];   // 57,344 B
    __shared__ int hist[NBINS];                 //  1,172 B
    __shared__ int off[NBINS];                  //  1,172 B
    const int tid = threadIdx.x;
    const long long e0 = (long long)blockIdx.x * EPB;
    long long rem = (long long)N_EDGES - e0;
    const int nE = (int)(rem < EPB ? rem : EPB);   // always a multiple of 4

    for (int i = tid; i < NBINS; i += 512) hist[i] = 0;
    __syncthreads();

    // phase 1: histogram over bins (LDS atomics), int4 loads
    for (int k = tid * 4; k < nE; k += 512 * 4) {
        int4 d4 = *(const int4*)(dst + e0 + k);
        atomicAdd(&hist[d4.x >> BIN_SHIFT], 1);
        atomicAdd(&hist[d4.y >> BIN_SHIFT], 1);
        atomicAdd(&hist[d4.z >> BIN_SHIFT], 1);
        atomicAdd(&hist[d4.w >> BIN_SHIFT], 1);
    }
    __syncthreads();

    // phase 2: Hillis-Steele inclusive scan -> exclusive offsets; emit info
    if (tid < NBINS) off[tid] = hist[tid];
    __syncthreads();
    for (int s = 1; s < NBINS; s <<= 1) {
        int v = 0;
        if (tid < NBINS && tid >= s) v = off[tid - s];
        __syncthreads();
        if (tid < NBINS && tid >= s) off[tid] += v;
        __syncthreads();
    }
    if (tid < NBINS) {
        int excl = off[tid] - hist[tid];
        off[tid] = excl;
        blk_info[(long long)tid * NBLK_A + blockIdx.x] =
            ((unsigned)excl << 16) | (unsigned)hist[tid];
    }
    __syncthreads();

    // phase 3: scatter into LDS stage (8-B LDS writes: no line thrash)
    for (int k = tid * 4; k < nE; k += 512 * 4) {
        int4   s4 = *(const int4*)(src + e0 + k);
        int4   d4 = *(const int4*)(dst + e0 + k);
        float4 w4 = *(const float4*)(w + e0 + k);
#define DO_EDGE(S, DD, W) { \
        unsigned q = (unsigned)((W) * 8191.0f + 0.5f); \
        int bin = (DD) >> BIN_SHIFT; \
        int pos = atomicAdd(&off[bin], 1); \
        stage[pos] = ((unsigned long long)(unsigned)((DD) & (BIN_NODES - 1)) << 32) \
                   | ((q << 19) | (unsigned)(S)); }
        DO_EDGE(s4.x, d4.x, w4.x)
        DO_EDGE(s4.y, d4.y, w4.y)
        DO_EDGE(s4.z, d4.z, w4.z)
        DO_EDGE(s4.w, d4.w, w4.w)
#undef DO_EDGE
    }
    __syncthreads();

    // phase 4: stream sorted block region to global (full-line u64 stores)
    for (int k = tid; k < nE; k += 512)
        seg[e0 + k] = stage[k];
}

// ---------------------------------------------------------------- pass B
// One block per bin, TWO phases over its (L2-hot, ~260 KB) fragments:
// phase 1 counts per (node, src-slice); phase 2 places slice-0 entries at
// [0, d0) and slice-1 entries at [s1, s1+d1), s1 = align4(d0), so both
// slice ranges support aligned uint4 reads in the gather. deg packs
// d0 | d1<<16. Slot stores confined to the bin's 384 KB region (L2-local).
__global__ __launch_bounds__(512) void binB_kernel(
        const unsigned*           __restrict__ blk_info,
        const unsigned long long* __restrict__ seg,
        int*      __restrict__ deg,
        unsigned* __restrict__ slots) {
    __shared__ int dl[BIN_NODES];        // packed counts c0 | c1<<16
    __shared__ int al[BIN_NODES];        // packed alloc cursors
    __shared__ unsigned info[NBLK_A];    // 5.4 KB
    const int bin = blockIdx.x;
    const int tid = threadIdx.x;
    dl[tid] = 0; dl[tid + 512] = 0;
    al[tid] = 0; al[tid + 512] = 0;
    for (int i = tid; i < NBLK_A; i += 512)
        info[i] = blk_info[(long long)bin * NBLK_A + i];
    __syncthreads();

    const int node0 = bin << BIN_SHIFT;
    const int grp = tid >> 5;            // 16 groups of 32 lanes
    const int gl  = tid & 31;
    int b1 = grp * BPG + BPG;
    if (b1 > NBLK_A) b1 = NBLK_A;

    // phase 1: count per (node, slice)
    for (int blk = grp * BPG; blk < b1; ++blk) {
        unsigned inf = info[blk];
        int cnt = (int)(inf & 0xFFFFu);
        long long base = (long long)blk * EPB + (inf >> 16);
        for (int j = gl; j < cnt; j += 32) {
            unsigned long long v = seg[base + j];
            int l = (int)(v >> 32);
            atomicAdd(&dl[l], (((unsigned)v & SRC_MASK) < SPLIT) ? 1 : 0x10000);
        }
    }
    __syncthreads();

    // phase 2: place
    for (int blk = grp * BPG; blk < b1; ++blk) {
        unsigned inf = info[blk];
        int cnt = (int)(inf & 0xFFFFu);
        long long base = (long long)blk * EPB + (inf >> 16);
        for (int j = gl; j < cnt; j += 32) {
            unsigned long long v = seg[base + j];
            int l = (int)(v >> 32);
            unsigned sv = (unsigned)v;
            int c  = dl[l];
            int d0 = min(c & 0xFFFF, CAP);
            int s1 = (d0 + 3) & ~3;
            int d1 = min(c >> 16, CAP - s1);
            long long sb = (long long)(node0 + l) * CAP;
            if ((sv & SRC_MASK) < SPLIT) {
                int p = atomicAdd(&al[l], 1) & 0xFFFF;
                if (p < d0) slots[sb + p] = sv;
            } else {
                int p = atomicAdd(&al[l], 0x10000) >> 16;
                if (p < d1) slots[sb + s1 + p] = sv;
            }
        }
    }
    __syncthreads();

    // write packed deg
    for (int k = tid; k < BIN_NODES; k += 512) {
        int node = node0 + k;
        if (node < N_NODES) {
            int c  = dl[k];
            int d0 = min(c & 0xFFFF, CAP);
            int s1 = (d0 + 3) & ~3;
            int d1 = min(c >> 16, CAP - s1);
            deg[node] = d0 | (d1 << 16);
        }
    }
}

// ---------------------------------------------------------------- gather SpMM
// FOUR nodes per wave: g = lane>>4 picks the node, c = lane&15 covers the
// 64-dim row as uint2 (8 B/lane x 16 lanes = 128-B row). Weight scale
// deferred inside a pass; fmaf(low2float(h), q, acc) fuses into
// v_fma_mix_f32. Two K-slice passes per layer:
//  MODE 0: pass 0 (src<SPLIT),  next = h(acc)            (fp16 partial)
//  MODE 1: pass 1 (src>=SPLIT), next += acc              (fp16 RMW)
//  MODE 2: last-layer pass 0,   out = acc                (fp32 partial)
//  MODE 3: last-layer pass 1,   out = (out+acc+x0+x1+x2)*0.25
template <int MODE>
__global__ void spmm_gather(const int*      __restrict__ deg,
                            const unsigned* __restrict__ slots,
                            const uint2*    __restrict__ cur,   // rows of 16 uint2
                            uint2*          __restrict__ next,
                            const uint2*    __restrict__ x0b,
                            const uint2*    __restrict__ x1b,
                            float4*         __restrict__ out) {
    long long t = (long long)blockIdx.x * blockDim.x + threadIdx.x;
    int wave = (int)(t >> 6);
    int lane = (int)(t & 63);
    int g    = lane >> 4;
    int c    = lane & 15;
    int node = wave * 4 + g;
    if (node >= N_NODES) return;
    int dd = deg[node];
    int i, end;
    if (MODE == 0 || MODE == 2) { i = 0; end = dd & 0xFFFF; }
    else { i = ((dd & 0xFFFF) + 3) & ~3; end = i + (dd >> 16); }
    const unsigned* sl = slots + (long long)node * CAP;
    float a0 = 0.f, a1 = 0.f, a2 = 0.f, a3 = 0.f;

#define GATHER(E) { \
        unsigned e_ = (E); \
        uint2 hv = cur[((long long)(e_ & SRC_MASK) << 4) + c]; \
        float q_ = (float)(e_ >> 19); \
        __half2 h01 = *reinterpret_cast<const __half2*>(&hv.x); \
        __half2 h23 = *reinterpret_cast<const __half2*>(&hv.y); \
        a0 = fmaf(__low2float(h01),  q_, a0); \
        a1 = fmaf(__high2float(h01), q_, a1); \
        a2 = fmaf(__low2float(h23),  q_, a2); \
        a3 = fmaf(__high2float(h23), q_, a3); }

    for (; i + 7 < end; i += 8) {      // 8 edges/group -> 32 rows in flight/wave
        uint4 ea = *(const uint4*)(sl + i);
        uint4 eb = *(const uint4*)(sl + i + 4);
        GATHER(ea.x) GATHER(ea.y) GATHER(ea.z) GATHER(ea.w)
        GATHER(eb.x) GATHER(eb.y) GATHER(eb.z) GATHER(eb.w)
    }
    for (; i + 3 < end; i += 4) {
        uint4 ea = *(const uint4*)(sl + i);
        GATHER(ea.x) GATHER(ea.y) GATHER(ea.z) GATHER(ea.w)
    }
    for (; i < end; ++i) {
        GATHER(sl[i])
    }
#undef GATHER

    a0 *= W_SCALE; a1 *= W_SCALE; a2 *= W_SCALE; a3 *= W_SCALE;
    long long oi = (long long)node * 16 + c;
    if (MODE == 0) {
        __half2 p01 = __float22half2_rn(make_float2(a0, a1));
        __half2 p23 = __float22half2_rn(make_float2(a2, a3));
        next[oi] = make_uint2(*reinterpret_cast<unsigned*>(&p01),
                              *reinterpret_cast<unsigned*>(&p23));
    } else if (MODE == 1) {
        uint2 pv = next[oi];
        __half2 q01 = *reinterpret_cast<const __half2*>(&pv.x);
        __half2 q23 = *reinterpret_cast<const __half2*>(&pv.y);
        a0 += __low2float(q01); a1 += __high2float(q01);
        a2 += __low2float(q23); a3 += __high2float(q23);
        __half2 p01 = __float22half2_rn(make_float2(a0, a1));
        __half2 p23 = __float22half2_rn(make_float2(a2, a3));
        next[oi] = make_uint2(*reinterpret_cast<unsigned*>(&p01),
                              *reinterpret_cast<unsigned*>(&p23));
    } else if (MODE == 2) {
        out[oi] = make_float4(a0, a1, a2, a3);
    } else {
        float4 o = out[oi];
        uint2 v0 = x0b[oi], v1 = x1b[oi], v2 = cur[oi];
        __half2 u01 = *reinterpret_cast<const __half2*>(&v0.x);
        __half2 u23 = *reinterpret_cast<const __half2*>(&v0.y);
        __half2 w01 = *reinterpret_cast<const __half2*>(&v1.x);
        __half2 w23 = *reinterpret_cast<const __half2*>(&v1.y);
        __half2 z01 = *reinterpret_cast<const __half2*>(&v2.x);
        __half2 z23 = *reinterpret_cast<const __half2*>(&v2.y);
        o.x = (o.x + a0 + __low2float(u01)  + __low2float(w01)  + __low2float(z01))  * 0.25f;
        o.y = (o.y + a1 + __high2float(u01) + __high2float(w01) + __high2float(z01)) * 0.25f;
        o.z = (o.z + a2 + __low2float(u23)  + __low2float(w23)  + __low2float(z23))  * 0.25f;
        o.w = (o.w + a3 + __high2float(u23) + __high2float(w23) + __high2float(z23)) * 0.25f;
        out[oi] = o;
    }
}

// ---------------------------------------------------------------- launch
extern "C" void kernel_launch(void* const* d_in, const int* in_sizes, int n_in,
                              void* d_out, int out_size, void* d_ws, size_t ws_size,
                              hipStream_t stream) {
    const float* user_emb = (const float*)d_in[0];
    const float* item_emb = (const float*)d_in[1];
    const float* ew       = (const float*)d_in[2];
    const int*   es       = (const int*)d_in[3];
    const int*   ed       = (const int*)d_in[4];
    float* out = (float*)d_out;

    // ws layout:
    //   slots    u32 x N_NODES*CAP       [0          .. 115,200,000)
    //   deg      int x N_NODES           [115.2M     .. 116,400,000)
    //   buf0     fp16 x NELEM  (x0)      [116.4M     .. 154,800,000)
    //   buf1     fp16 x NELEM  (x1)      [154.8M     .. 193,200,000)
    //   buf2     fp16 x NELEM  (x2)      [193.2M     .. 231,600,000)
    //   blk_info u32 x NBINS*NBLK_A      [231.6M     .. 233,170,480)
    //   seg      u64 x NBLK_A*EPB overlays buf0..buf2-head (dead before init)
    // max ~233.2 MB (verified 235 MB fits). Stream order makes overlays safe.
    unsigned* slots = (unsigned*)d_ws;
    int*      deg   = (int*)(slots + (long long)N_NODES * CAP);
    __half*   buf0  = (__half*)(deg + N_NODES);
    __half*   buf1  = buf0 + NELEM;
    __half*   buf2  = buf1 + NELEM;
    unsigned* blk_info = (unsigned*)(buf2 + NELEM);
    unsigned long long* seg = (unsigned long long*)buf0;

    const int B = 256;
    const long long node_waves  = (N_NODES + 3) / 4;                       // 75000
    const long long node_blocks = (node_waves * 64 + B - 1) / B;           // 18750
    const long long init_blocks = (NELEM4 + B - 1) / B;

    // ---- LDS-staged binned bucket build (no global atomics, no memset) ----
    binA_kernel<<<dim3((unsigned)NBLK_A), dim3(512), 0, stream>>>(
        es, ed, ew, seg, blk_info);
    binB_kernel<<<dim3((unsigned)NBINS), dim3(512), 0, stream>>>(
        blk_info, seg, deg, slots);

    // cur = fp16(all_emb). After binB (seg overlay).
    init_kernel<<<dim3((unsigned)init_blocks), dim3(B), 0, stream>>>(
        (const float4*)user_emb, (const float4*)item_emb, (ushort4*)buf0);

    dim3 ng((unsigned)node_blocks), nb(B);
    // ---- 3 gather layers, each as 2 K-slice passes ----
    spmm_gather<0><<<ng, nb, 0, stream>>>(deg, slots, (const uint2*)buf0,
        (uint2*)buf1, nullptr, nullptr, nullptr);
    spmm_gather<1><<<ng, nb, 0, stream>>>(deg, slots, (const uint2*)buf0,
        (uint2*)buf1, nullptr, nullptr, nullptr);
    spmm_gather<0><<<ng, nb, 0, stream>>>(deg, slots, (const uint2*)buf1,
        (uint2*)buf2, nullptr, nullptr, nullptr);
    spmm_gather<1><<<ng, nb, 0, stream>>>(deg, slots, (const uint2*)buf1,
        (uint2*)buf2, nullptr, nullptr, nullptr);
    spmm_gather<2><<<ng, nb, 0, stream>>>(deg, slots, (const uint2*)buf2,
        nullptr, nullptr, nullptr, (float4*)out);
    spmm_gather<3><<<ng, nb, 0, stream>>>(deg, slots, (const uint2*)buf2,
        nullptr, (const uint2*)buf0, (const uint2*)buf1, (float4*)out);
}

// Round 6
// 877.686 us; speedup vs baseline: 1.1140x; 1.1140x over previous
//
#include <hip/hip_runtime.h>
#include <hip/hip_fp16.h>

#define USER_NUM 200000
#define ITEM_NUM 100000
#define N_NODES  300000   // USER_NUM + ITEM_NUM
#define N_EDGES  9600000
#define D        64
#define NELEM    ((long long)N_NODES * D)       // 19,200,000
#define NELEM4   (NELEM / 4)                    // 4,800,000

// Fixed-capacity bucket per node. deg ~ Poisson(32), max for this dataset
// ~60; CAP=96 leaves huge margin (clamp guards below make OOB impossible).
#define CAP 96

// Slot entry packing: [31:19] = 13-bit weight q (w = q/8191), [18:0] = src id.
#define SRC_MASK 0x7FFFFu
#define W_SCALE  (1.0f / 8191.0f)

// ---- binned bucket-build geometry ----
// Round-1 lesson: scatter through global cache lines thrashes when open
// partial lines exceed per-XCD L2. Round-5 lesson: that applies to binB's
// slot scatter too (293 concurrent bins = 7-14 MB of windows per 4 MB L2,
// WRITE 282 MB for 38 MB of data). Fix: persistent binB with GRID_B=160
// blocks -> 20 bins/XCD x 192 KB = 3.8 MB of active windows, fits L2.
#define BIN_NODES 512
#define BIN_SHIFT 9
#define NBINS     ((N_NODES + BIN_NODES - 1) / BIN_NODES)   // 586
#define EPB       7168    // edges per binA block (56 KB LDS stage)
#define NBLK_A    ((N_EDGES + EPB - 1) / EPB)               // 1340
#define GRID_B    160     // binB concurrency bound (L2 window budget)
#define BPG       ((NBLK_A + 31) / 32)                      // 42 frags/group

// ---------------------------------------------------------------- init
// cur = fp16(all_emb). Final layer reconstructs the layer-sum from the
// per-layer fp16 buffers, so out is never RMW'd across layers.
__global__ void init_kernel(const float4* __restrict__ user_emb,
                            const float4* __restrict__ item_emb,
                            ushort4* __restrict__ cur) {
    long long i = (long long)blockIdx.x * blockDim.x + threadIdx.x;
    if (i >= NELEM4) return;
    const long long user4 = (long long)USER_NUM * D / 4;
    float4 v = (i < user4) ? user_emb[i] : item_emb[i - user4];
    __half h0 = __float2half_rn(v.x), h1 = __float2half_rn(v.y);
    __half h2 = __float2half_rn(v.z), h3 = __float2half_rn(v.w);
    cur[i] = make_ushort4(*(unsigned short*)&h0, *(unsigned short*)&h1,
                          *(unsigned short*)&h2, *(unsigned short*)&h3);
}

// ---------------------------------------------------------------- pass A
// Block-local counting sort of EPB edges by bin (586 bins of 512 nodes),
// staged in LDS, streamed out as full lines. Entry:
// u64 = (local_node << 32) | (q << 19) | src.
// blk_info[bin][blk] = (start_in_block << 16) | count.
// Scan over 586 bins > 512 threads: 2 bins/thread chunk + Hillis-Steele
// over 512 chunk sums (in-place in hist[]).
__global__ __launch_bounds__(512) void binA_kernel(
        const int*   __restrict__ src,
        const int*   __restrict__ dst,
        const float* __restrict__ w,
        unsigned long long* __restrict__ seg,
        unsigned*           __restrict__ blk_info) {
    __shared__ unsigned long long stage[EPB];   // 57,344 B
    __shared__ int hist[NBINS];                 //  2,344 B (reused as scan tmp)
    __shared__ int off[NBINS];                  //  2,344 B
    const int tid = threadIdx.x;
    const long long e0 = (long long)blockIdx.x * EPB;
    long long rem = (long long)N_EDGES - e0;
    const int nE = (int)(rem < EPB ? rem : EPB);   // always a multiple of 4

    for (int i = tid; i < NBINS; i += 512) hist[i] = 0;
    __syncthreads();

    // phase 1: histogram over bins (LDS atomics), int4 loads
    for (int k = tid * 4; k < nE; k += 512 * 4) {
        int4 d4 = *(const int4*)(dst + e0 + k);
        atomicAdd(&hist[d4.x >> BIN_SHIFT], 1);
        atomicAdd(&hist[d4.y >> BIN_SHIFT], 1);
        atomicAdd(&hist[d4.z >> BIN_SHIFT], 1);
        atomicAdd(&hist[d4.w >> BIN_SHIFT], 1);
    }
    __syncthreads();

    // phase 2: exclusive scan (2 bins per thread chunk)
    int c0 = (2 * tid     < NBINS) ? hist[2 * tid]     : 0;
    int c1 = (2 * tid + 1 < NBINS) ? hist[2 * tid + 1] : 0;
    __syncthreads();
    hist[tid] = c0 + c1;           // chunk sums, in-place over hist[0..511]
    __syncthreads();
    for (int s = 1; s < 512; s <<= 1) {
        int v = (tid >= s) ? hist[tid - s] : 0;
        __syncthreads();
        if (tid >= s) hist[tid] += v;
        __syncthreads();
    }
    int base = (tid > 0) ? hist[tid - 1] : 0;   // exclusive chunk base
    if (2 * tid < NBINS) {
        off[2 * tid] = base;
        blk_info[(long long)(2 * tid) * NBLK_A + blockIdx.x] =
            ((unsigned)base << 16) | (unsigned)c0;
    }
    if (2 * tid + 1 < NBINS) {
        off[2 * tid + 1] = base + c0;
        blk_info[(long long)(2 * tid + 1) * NBLK_A + blockIdx.x] =
            ((unsigned)(base + c0) << 16) | (unsigned)c1;
    }
    __syncthreads();

    // phase 3: scatter into LDS stage (8-B LDS writes: no line thrash)
    for (int k = tid * 4; k < nE; k += 512 * 4) {
        int4   s4 = *(const int4*)(src + e0 + k);
        int4   d4 = *(const int4*)(dst + e0 + k);
        float4 w4 = *(const float4*)(w + e0 + k);
#define DO_EDGE(S, DD, W) { \
        unsigned q = (unsigned)((W) * 8191.0f + 0.5f); \
        int bin = (DD) >> BIN_SHIFT; \
        int pos = atomicAdd(&off[bin], 1); \
        stage[pos] = ((unsigned long long)(unsigned)((DD) & (BIN_NODES - 1)) << 32) \
                   | ((q << 19) | (unsigned)(S)); }
        DO_EDGE(s4.x, d4.x, w4.x)
        DO_EDGE(s4.y, d4.y, w4.y)
        DO_EDGE(s4.z, d4.z, w4.z)
        DO_EDGE(s4.w, d4.w, w4.w)
#undef DO_EDGE
    }
    __syncthreads();

    // phase 4: stream sorted block region to global (full-line u64 stores)
    for (int k = tid; k < nE; k += 512)
        seg[e0 + k] = stage[k];
}

// ---------------------------------------------------------------- pass B
// Persistent: GRID_B blocks, each walks bins bin = blockIdx, +GRID_B, ...
// Bounded concurrency keeps active slot windows (20/XCD x 192 KB = 3.8 MB)
// inside per-XCD L2 so scattered 4-B stores coalesce into full lines before
// writeback (round-5 PMC: unbounded version wrote 282 MB for 38 MB data).
// Fragments (mean 12.2 edges) are walked by 16-lane groups.
__global__ __launch_bounds__(512) void binB_kernel(
        const unsigned*           __restrict__ blk_info,
        const unsigned long long* __restrict__ seg,
        int*      __restrict__ deg,
        unsigned* __restrict__ slots) {
    __shared__ int dl[BIN_NODES];        // 2 KB
    __shared__ unsigned info[NBLK_A];    // 5.4 KB
    const int tid = threadIdx.x;
    const int grp = tid >> 4;            // 32 groups of 16 lanes
    const int gl  = tid & 15;

    for (int bin = blockIdx.x; bin < NBINS; bin += GRID_B) {
        dl[tid] = 0;
        for (int i = tid; i < NBLK_A; i += 512)
            info[i] = blk_info[(long long)bin * NBLK_A + i];
        __syncthreads();

        const int node0 = bin << BIN_SHIFT;
        int b0 = grp * BPG;
        int b1 = b0 + BPG; if (b1 > NBLK_A) b1 = NBLK_A;
        for (int blk = b0; blk < b1; ++blk) {
            unsigned inf = info[blk];
            int cnt = (int)(inf & 0xFFFFu);
            long long base = (long long)blk * EPB + (inf >> 16);
            for (int j = gl; j < cnt; j += 16) {
                unsigned long long v = seg[base + j];
                int l = (int)(v >> 32);
                int p = atomicAdd(&dl[l], 1);
                if (p < CAP) slots[(long long)(node0 + l) * CAP + p] = (unsigned)v;
            }
        }
        __syncthreads();

        int node = node0 + tid;
        if (node < N_NODES) deg[node] = min(dl[tid], CAP);
        __syncthreads();    // dl/info reused next bin
    }
}

// ---------------------------------------------------------------- gather SpMM
// FOUR nodes per wave: g = lane>>4 picks the node, c = lane&15 covers the
// 64-dim row as uint2 (8 B/lane x 16 lanes = 128-B row). Weight scale
// deferred to the epilogue; fmaf(low2float(h), q, acc) fuses into
// v_fma_mix_f32.
// MLP: the first 16 entries are loaded UNCONDITIONALLY (the CAP bucket is
// always mapped); invalid entries (i >= n) are zero-selected BEFORE address
// compute (entry 0 -> src 0 row, q 0 -> contributes exactly 0; avoids
// 0 x NaN from poisoned workspace). This removes the deg dependency from
// the head burst: 16 gathers + deg in flight immediately per node.
template <bool LAST>
__global__ void spmm_gather(const int*      __restrict__ deg,
                            const unsigned* __restrict__ slots,
                            const uint2*    __restrict__ cur,   // rows of 16 uint2
                            uint2*          __restrict__ next,
                            const uint2*    __restrict__ x0b,
                            const uint2*    __restrict__ x1b,
                            float4*         __restrict__ out) {
    long long t = (long long)blockIdx.x * blockDim.x + threadIdx.x;
    int wave = (int)(t >> 6);
    int lane = (int)(t & 63);
    int g    = lane >> 4;
    int c    = lane & 15;
    int node = wave * 4 + g;
    if (node >= N_NODES) return;
    const unsigned* sl = slots + (long long)node * CAP;
    int n = deg[node];                 // pre-clamped to CAP in binB
    float a0 = 0.f, a1 = 0.f, a2 = 0.f, a3 = 0.f;

#define GATHER(E) { \
        unsigned e_ = (E); \
        uint2 hv = cur[((long long)(e_ & SRC_MASK) << 4) + c]; \
        float q_ = (float)(e_ >> 19); \
        __half2 h01 = *reinterpret_cast<const __half2*>(&hv.x); \
        __half2 h23 = *reinterpret_cast<const __half2*>(&hv.y); \
        a0 = fmaf(__low2float(h01),  q_, a0); \
        a1 = fmaf(__high2float(h01), q_, a1); \
        a2 = fmaf(__low2float(h23),  q_, a2); \
        a3 = fmaf(__high2float(h23), q_, a3); }
#define GP(E, I) { unsigned ep_ = ((I) < n) ? (E) : 0u; GATHER(ep_) }

    {   // unconditional predicated 16-burst (P(deg<16) ~ 0.07%)
        uint4 ea = *(const uint4*)(sl + 0);
        uint4 eb = *(const uint4*)(sl + 4);
        uint4 ec = *(const uint4*)(sl + 8);
        uint4 ed = *(const uint4*)(sl + 12);
        GP(ea.x, 0)  GP(ea.y, 1)  GP(ea.z, 2)  GP(ea.w, 3)
        GP(eb.x, 4)  GP(eb.y, 5)  GP(eb.z, 6)  GP(eb.w, 7)
        GP(ec.x, 8)  GP(ec.y, 9)  GP(ec.z, 10) GP(ec.w, 11)
        GP(ed.x, 12) GP(ed.y, 13) GP(ed.z, 14) GP(ed.w, 15)
    }
    int i = 16;
    for (; i + 7 < n; i += 8) {
        uint4 ea = *(const uint4*)(sl + i);
        uint4 eb = *(const uint4*)(sl + i + 4);
        GATHER(ea.x) GATHER(ea.y) GATHER(ea.z) GATHER(ea.w)
        GATHER(eb.x) GATHER(eb.y) GATHER(eb.z) GATHER(eb.w)
    }
    for (; i + 3 < n; i += 4) {
        uint4 ea = *(const uint4*)(sl + i);
        GATHER(ea.x) GATHER(ea.y) GATHER(ea.z) GATHER(ea.w)
    }
    for (; i < n; ++i) {
        GATHER(sl[i])
    }
#undef GP
#undef GATHER

    a0 *= W_SCALE; a1 *= W_SCALE; a2 *= W_SCALE; a3 *= W_SCALE;
    long long oi = (long long)node * 16 + c;
    if (!LAST) {
        __half2 p01 = __float22half2_rn(make_float2(a0, a1));
        __half2 p23 = __float22half2_rn(make_float2(a2, a3));
        next[oi] = make_uint2(*reinterpret_cast<unsigned*>(&p01),
                              *reinterpret_cast<unsigned*>(&p23));
    } else {
        uint2 v0 = x0b[oi], v1 = x1b[oi], v2 = cur[oi];
        __half2 u01 = *reinterpret_cast<const __half2*>(&v0.x);
        __half2 u23 = *reinterpret_cast<const __half2*>(&v0.y);
        __half2 w01 = *reinterpret_cast<const __half2*>(&v1.x);
        __half2 w23 = *reinterpret_cast<const __half2*>(&v1.y);
        __half2 z01 = *reinterpret_cast<const __half2*>(&v2.x);
        __half2 z23 = *reinterpret_cast<const __half2*>(&v2.y);
        float4 o;
        o.x = (a0 + __low2float(u01)  + __low2float(w01)  + __low2float(z01))  * 0.25f;
        o.y = (a1 + __high2float(u01) + __high2float(w01) + __high2float(z01)) * 0.25f;
        o.z = (a2 + __low2float(u23)  + __low2float(w23)  + __low2float(z23))  * 0.25f;
        o.w = (a3 + __high2float(u23) + __high2float(w23) + __high2float(z23)) * 0.25f;
        out[oi] = o;
    }
}

// ---------------------------------------------------------------- launch
extern "C" void kernel_launch(void* const* d_in, const int* in_sizes, int n_in,
                              void* d_out, int out_size, void* d_ws, size_t ws_size,
                              hipStream_t stream) {
    const float* user_emb = (const float*)d_in[0];
    const float* item_emb = (const float*)d_in[1];
    const float* ew       = (const float*)d_in[2];
    const int*   es       = (const int*)d_in[3];
    const int*   ed       = (const int*)d_in[4];
    float* out = (float*)d_out;

    // ws layout:
    //   slots    u32 x N_NODES*CAP       [0          .. 115,200,000)
    //   deg      int x N_NODES           [115.2M     .. 116,400,000)
    //   buf0     fp16 x NELEM  (x0)      [116.4M     .. 154,800,000)
    //   buf1     fp16 x NELEM  (x1)      [154.8M     .. 193,200,000)
    //   buf2     fp16 x NELEM  (x2)      [193.2M     .. 231,600,000)
    //   seg      u64, overlays buf0+buf1 (valid entries end at 76.8 MB;
    //            dead before init_kernel writes buf0)
    //   blk_info u32 x NBINS*NBLK_A = 3.14 MB, overlays buf2 head (dead
    //            before layer-2 first writes buf2)
    // max touched 231.6 MB (verified fit). Stream order makes overlays safe.
    unsigned* slots = (unsigned*)d_ws;
    int*      deg   = (int*)(slots + (long long)N_NODES * CAP);
    __half*   buf0  = (__half*)(deg + N_NODES);
    __half*   buf1  = buf0 + NELEM;
    __half*   buf2  = buf1 + NELEM;
    unsigned long long* seg = (unsigned long long*)buf0;
    unsigned* blk_info = (unsigned*)buf2;

    const int B = 256;
    const long long node_waves  = (N_NODES + 3) / 4;                       // 75000
    const long long node_blocks = (node_waves * 64 + B - 1) / B;           // 18750
    const long long init_blocks = (NELEM4 + B - 1) / B;

    // ---- LDS-staged binned bucket build ----
    binA_kernel<<<dim3((unsigned)NBLK_A), dim3(512), 0, stream>>>(
        es, ed, ew, seg, blk_info);
    binB_kernel<<<dim3(GRID_B), dim3(512), 0, stream>>>(
        blk_info, seg, deg, slots);

    // cur = fp16(all_emb). After binB (seg overlay).
    init_kernel<<<dim3((unsigned)init_blocks), dim3(B), 0, stream>>>(
        (const float4*)user_emb, (const float4*)item_emb, (ushort4*)buf0);

    dim3 ng((unsigned)node_blocks), nb(B);
    // ---- 3 gather layers; final mean fused into layer 3 ----
    spmm_gather<false><<<ng, nb, 0, stream>>>(deg, slots, (const uint2*)buf0,
        (uint2*)buf1, nullptr, nullptr, nullptr);
    spmm_gather<false><<<ng, nb, 0, stream>>>(deg, slots, (const uint2*)buf1,
        (uint2*)buf2, nullptr, nullptr, nullptr);
    spmm_gather<true><<<ng, nb, 0, stream>>>(deg, slots, (const uint2*)buf2,
        nullptr, (const uint2*)buf0, (const uint2*)buf1, (float4*)out);
}